// Round 1
// baseline (243.174 us; speedup 1.0000x reference)
//
#include <hip/hip_runtime.h>

typedef unsigned short u16;
typedef unsigned int u32;
typedef unsigned long long u64;
typedef __attribute__((ext_vector_type(8))) short s16x8;
typedef __attribute__((ext_vector_type(8))) __bf16 bf16x8;
typedef __attribute__((ext_vector_type(4))) float fx4;

// ---------- helpers ----------
__device__ __forceinline__ fx4 mfma_16x16x32(s16x8 a, s16x8 b, fx4 c) {
  return __builtin_amdgcn_mfma_f32_16x16x32_bf16(
      __builtin_bit_cast(bf16x8, a), __builtin_bit_cast(bf16x8, b), c, 0, 0, 0);
}

__device__ __forceinline__ u16 f2bf(float f) {
  u32 u = __builtin_bit_cast(u32, f);
  u32 r = u + 0x7fffu + ((u >> 16) & 1u);
  return (u16)(r >> 16);
}
__device__ __forceinline__ float bf2f(u16 h) {
  u32 u = ((u32)h) << 16;
  return __builtin_bit_cast(float, u);
}

__device__ __forceinline__ void gload16(const void* g, void* l) {
  __builtin_amdgcn_global_load_lds(
      (const __attribute__((address_space(1))) u32*)g,
      (__attribute__((address_space(3))) u32*)l, 16, 0, 0);
}

// ---------- constants ----------
#define B_ 2
#define T_ 2048
#define C_ 1024
#define H_ 16
#define HD_ 64
#define BH_ 32
#define M_ 4096   // B*T

// ---------- prep kernels ----------
__global__ void rope_table_k(float* __restrict__ ct, float* __restrict__ st) {
  int id = blockIdx.x * 256 + threadIdx.x;          // 65536 = T*32
  int t = id >> 5, i = id & 31;
  // inv_freq = 10000^(-i/32) = exp2(-i * log2(10000)/32)
  float f = exp2f(-(float)i * (13.287712379549449f / 32.0f));
  float a = (float)t * f;
  float s, c;
  sincosf(a, &s, &c);
  ct[id] = c;
  st[id] = s;
}

__global__ void cvt_f32_bf16_k(const float* __restrict__ in, u16* __restrict__ outp) {
  int id = blockIdx.x * 256 + threadIdx.x;          // each handles 8 elems
  const fx4* p = (const fx4*)(in + (u64)id * 8);
  fx4 v0 = p[0], v1 = p[1];
  s16x8 r;
#pragma unroll
  for (int j = 0; j < 4; ++j) {
    r[j] = (short)f2bf(v0[j]);
    r[4 + j] = (short)f2bf(v1[j]);
  }
  *((s16x8*)outp + id) = r;
}

// W [R][Ncols] f32  ->  WT [Ncols][R] bf16
__global__ void transpose_w_k(const float* __restrict__ W, u16* __restrict__ WT,
                              int Ncols, int R) {
  __shared__ u16 T_s[64 * 72];
  int c0 = blockIdx.x * 64, r0 = blockIdx.y * 64;
  int tid = threadIdx.x;
#pragma unroll
  for (int it = 0; it < 4; ++it) {
    int idx = it * 256 + tid;
    int r = idx >> 4, c4 = (idx & 15) * 4;
    fx4 v = *(const fx4*)(W + (u64)(r0 + r) * Ncols + c0 + c4);
#pragma unroll
    for (int j = 0; j < 4; ++j) T_s[(c4 + j) * 72 + r] = f2bf(v[j]);
  }
  __syncthreads();
#pragma unroll
  for (int it = 0; it < 2; ++it) {
    int idx = it * 256 + tid;
    int rc = idx >> 3, c8 = (idx & 7) * 8;
    s16x8 v = *(const s16x8*)(T_s + rc * 72 + c8);
    *(s16x8*)(WT + (u64)(c0 + rc) * R + r0 + c8) = v;
  }
}

// v [BH][T][64] bf16 -> vt [BH][64][T] bf16
__global__ void transpose_v_k(const u16* __restrict__ V, u16* __restrict__ VT) {
  __shared__ u16 T_s[64 * 72];
  int t0 = blockIdx.x * 64;
  int bh = blockIdx.y;
  int tid = threadIdx.x;
#pragma unroll
  for (int it = 0; it < 2; ++it) {
    int idx = it * 256 + tid;
    int t = idx >> 3, c8 = (idx & 7) * 8;
    s16x8 v = *(const s16x8*)(V + ((u64)bh * T_ + t0 + t) * HD_ + c8);
#pragma unroll
    for (int j = 0; j < 8; ++j) T_s[(c8 + j) * 72 + t] = (u16)v[j];
  }
  __syncthreads();
#pragma unroll
  for (int it = 0; it < 2; ++it) {
    int idx = it * 256 + tid;
    int d = idx >> 3, t8 = (idx & 7) * 8;
    s16x8 v = *(const s16x8*)(T_s + d * 72 + t8);
    *(s16x8*)(VT + ((u64)bh * HD_ + d) * T_ + t0 + t8) = v;
  }
}

// in-place RoPE on X [BH][T][64] bf16, half-split layout
__global__ void rope_apply_k(u16* __restrict__ X, const float* __restrict__ ct,
                             const float* __restrict__ st) {
  int id = blockIdx.x * 256 + threadIdx.x;          // BH*T*4
  int row = id >> 2, q = id & 3;
  int t = row & (T_ - 1);
  int d0 = q * 8;
  u16* plo = X + (u64)row * HD_ + d0;
  u16* phi = plo + 32;
  s16x8 lo = *(const s16x8*)plo, hi = *(const s16x8*)phi;
  s16x8 olo, ohi;
#pragma unroll
  for (int j = 0; j < 8; ++j) {
    float c = ct[t * 32 + d0 + j];
    float s = st[t * 32 + d0 + j];
    float l = bf2f((u16)lo[j]), h = bf2f((u16)hi[j]);
    olo[j] = (short)f2bf(l * c - h * s);
    ohi[j] = (short)f2bf(h * c + l * s);
  }
  *(s16x8*)plo = olo;
  *(s16x8*)phi = ohi;
}

// ---------- GEMM: A[M][K] bf16 @ B[N][K]^T bf16, 128x128 tile, m97 structure ----------
// EPI==0: C fp32 [M][N].  EPI==1: scatter to q/k/v [BH][T][64] bf16.
template <int EPI>
__global__ __launch_bounds__(256, 2) void gemm_bt_k(
    const u16* __restrict__ A, const u16* __restrict__ B, float* __restrict__ C,
    u16* __restrict__ Qo, u16* __restrict__ Ko, u16* __restrict__ Vo,
    int M, int N, int K) {
  __shared__ u16 As[128 * 32];
  __shared__ u16 Bs[128 * 32];
  int tid = threadIdx.x, lane = tid & 63, w = tid >> 6;
  int wm = w >> 1, wn = w & 1, l15 = lane & 15, l4 = lane >> 4;
  int m0 = blockIdx.y * 128, n0 = blockIdx.x * 128;
  fx4 acc[4][4] = {};
  int arow = tid >> 2, ac8 = (tid & 3) * 8;
  const u16* Ab = A + (u64)(m0 + arow) * K + ac8;
  const u16* Bb = B + (u64)(n0 + arow) * K + ac8;
  char* AsB = (char*)As + tid * 16;
  char* BsB = (char*)Bs + tid * 16;

  for (int k0 = 0; k0 < K; k0 += 32) {
    __syncthreads();
    gload16(Ab + k0, AsB);
    gload16(Ab + (u64)64 * K + k0, AsB + 4096);
    gload16(Bb + k0, BsB);
    gload16(Bb + (u64)64 * K + k0, BsB + 4096);
    __syncthreads();
    s16x8 a[4], b[4];
#pragma unroll
    for (int mi = 0; mi < 4; ++mi)
      a[mi] = *(const s16x8*)((const char*)As + (wm * 64 + mi * 16 + l15) * 64 + l4 * 16);
#pragma unroll
    for (int ni = 0; ni < 4; ++ni)
      b[ni] = *(const s16x8*)((const char*)Bs + (wn * 64 + ni * 16 + l15) * 64 + l4 * 16);
#pragma unroll
    for (int mi = 0; mi < 4; ++mi)
#pragma unroll
      for (int ni = 0; ni < 4; ++ni)
        acc[mi][ni] = mfma_16x16x32(a[mi], b[ni], acc[mi][ni]);
  }

  if (EPI == 0) {
#pragma unroll
    for (int mi = 0; mi < 4; ++mi)
#pragma unroll
      for (int ni = 0; ni < 4; ++ni)
#pragma unroll
        for (int r = 0; r < 4; ++r) {
          u64 row = (u64)(m0 + wm * 64 + mi * 16 + l4 * 4 + r);
          int col = n0 + wn * 64 + ni * 16 + l15;
          C[row * N + col] = acc[mi][ni][r];
        }
  } else {
#pragma unroll
    for (int mi = 0; mi < 4; ++mi)
#pragma unroll
      for (int ni = 0; ni < 4; ++ni)
#pragma unroll
        for (int r = 0; r < 4; ++r) {
          int row = m0 + wm * 64 + mi * 16 + l4 * 4 + r;
          int col = n0 + wn * 64 + ni * 16 + l15;
          int b2 = row >> 11, t = row & (T_ - 1);
          int qi = col >> 10, h = (col >> 6) & 15, d = col & 63;
          u16* dst = (qi == 0 ? Qo : (qi == 1 ? Ko : Vo));
          dst[(((u64)(b2 * H_ + h)) * T_ + t) * HD_ + d] = f2bf(acc[mi][ni][r]);
        }
  }
}

// ---------- flash attention ----------
// Q,K [BH][T][64] bf16 (RoPE'd), Vt [BH][64][T] bf16, Y [B][T][C] bf16
__global__ __launch_bounds__(256, 2) void attn_fwd_k(
    const u16* __restrict__ Qb, const u16* __restrict__ Kb,
    const u16* __restrict__ Vt, u16* __restrict__ Y) {
  __shared__ u16 Ks[64 * 64];       // [key][d], XOR-swizzled
  __shared__ u16 Vs[64 * 64];       // [d][key], XOR-swizzled
  __shared__ u16 Ps[4][32 * 72];    // per-wave P, padded stride 72
  int qt = blockIdx.x, bh = blockIdx.y;
  int b2 = bh >> 4, h = bh & 15;
  int tid = threadIdx.x, lane = tid & 63, w = tid >> 6;
  int l15 = lane & 15, l4 = lane >> 4;
  int q0 = qt * 128, qw = q0 + w * 32;

  // Q fragments in registers (rows qw..qw+31, K = hd = 64 -> 2 k-steps)
  s16x8 aq[2][2];
#pragma unroll
  for (int mi = 0; mi < 2; ++mi)
#pragma unroll
    for (int ks = 0; ks < 2; ++ks)
      aq[mi][ks] = *(const s16x8*)(Qb + ((u64)(bh * T_ + qw + mi * 16 + l15)) * HD_ +
                                   ks * 32 + l4 * 8);

  fx4 o[2][4] = {};
  float mr[2][4], lr[2][4];
#pragma unroll
  for (int mi = 0; mi < 2; ++mi)
#pragma unroll
    for (int r = 0; r < 4; ++r) { mr[mi][r] = -3.0e38f; lr[mi][r] = 0.f; }

  const float cf = 0.18033688011112042f;  // (1/sqrt(64)) * log2(e)
  int nkv = 2 * qt + 2;

  for (int kv = 0; kv < nkv; ++kv) {
    __syncthreads();
    // stage K tile [64 keys][64 d] and Vt tile [64 d][64 keys], swizzled
#pragma unroll
    for (int it = 0; it < 2; ++it) {
      int idx = it * 256 + tid;
      int r = idx >> 3, c8 = idx & 7;
      s16x8 kval = *(const s16x8*)(Kb + ((u64)(bh * T_ + kv * 64 + r)) * HD_ + c8 * 8);
      *(s16x8*)((char*)Ks + ((r * 128 + c8 * 16) ^ ((r & 7) << 4))) = kval;
      s16x8 vval = *(const s16x8*)(Vt + ((u64)(bh * HD_ + r)) * T_ + kv * 64 + c8 * 8);
      *(s16x8*)((char*)Vs + ((r * 128 + c8 * 16) ^ ((r & 7) << 4))) = vval;
    }
    __syncthreads();

    if (kv * 64 <= qw + 31) {  // not fully masked for this wave
      // S = Q K^T
      fx4 s[2][4] = {};
#pragma unroll
      for (int ni = 0; ni < 4; ++ni) {
        int key = ni * 16 + l15;
#pragma unroll
        for (int ks = 0; ks < 2; ++ks) {
          s16x8 bk = *(const s16x8*)((const char*)Ks +
                       ((key * 128 + ks * 64 + l4 * 16) ^ ((key & 7) << 4)));
#pragma unroll
          for (int mi = 0; mi < 2; ++mi)
            s[mi][ni] = mfma_16x16x32(aq[mi][ks], bk, s[mi][ni]);
        }
      }
      // scale + causal mask
      bool needmask = (kv * 64 + 63) > qw;
#pragma unroll
      for (int mi = 0; mi < 2; ++mi)
#pragma unroll
        for (int ni = 0; ni < 4; ++ni)
#pragma unroll
          for (int r = 0; r < 4; ++r) {
            float sv = s[mi][ni][r] * cf;
            if (needmask) {
              int key = kv * 64 + ni * 16 + l15;
              int qr = qw + mi * 16 + l4 * 4 + r;
              if (key > qr) sv = -1e30f;
            }
            s[mi][ni][r] = sv;
          }
      // online softmax (row = (mi, l4, r); reduce over 16 lanes sharing l4)
#pragma unroll
      for (int mi = 0; mi < 2; ++mi)
#pragma unroll
        for (int r = 0; r < 4; ++r) {
          float rm = fmaxf(fmaxf(s[mi][0][r], s[mi][1][r]),
                           fmaxf(s[mi][2][r], s[mi][3][r]));
#pragma unroll
          for (int msk = 1; msk < 16; msk <<= 1)
            rm = fmaxf(rm, __shfl_xor(rm, msk, 64));
          float mold = mr[mi][r];
          float mnew = fmaxf(mold, rm);
          float corr = exp2f(mold - mnew);
          float rs = 0.f;
#pragma unroll
          for (int ni = 0; ni < 4; ++ni) {
            float p = exp2f(s[mi][ni][r] - mnew);
            s[mi][ni][r] = p;
            rs += p;
          }
#pragma unroll
          for (int msk = 1; msk < 16; msk <<= 1) rs += __shfl_xor(rs, msk, 64);
          lr[mi][r] = lr[mi][r] * corr + rs;
          mr[mi][r] = mnew;
#pragma unroll
          for (int di = 0; di < 4; ++di) o[mi][di][r] *= corr;
        }
      // P -> LDS (bf16)
#pragma unroll
      for (int mi = 0; mi < 2; ++mi)
#pragma unroll
        for (int ni = 0; ni < 4; ++ni)
#pragma unroll
          for (int r = 0; r < 4; ++r)
            Ps[w][(mi * 16 + l4 * 4 + r) * 72 + ni * 16 + l15] = f2bf(s[mi][ni][r]);
      // O += P V   (A = P[q][key], B = V^T[key->k][d->n] from Vs[d][key])
#pragma unroll
      for (int ks = 0; ks < 2; ++ks) {
        s16x8 ap[2], bv[4];
#pragma unroll
        for (int mi = 0; mi < 2; ++mi)
          ap[mi] = *(const s16x8*)((const char*)Ps[w] + (mi * 16 + l15) * 144 +
                                   ks * 64 + l4 * 16);
#pragma unroll
        for (int di = 0; di < 4; ++di) {
          int d = di * 16 + l15;
          bv[di] = *(const s16x8*)((const char*)Vs +
                     ((d * 128 + ks * 64 + l4 * 16) ^ ((d & 7) << 4)));
        }
#pragma unroll
        for (int mi = 0; mi < 2; ++mi)
#pragma unroll
          for (int di = 0; di < 4; ++di)
            o[mi][di] = mfma_16x16x32(ap[mi], bv[di], o[mi][di]);
      }
    }
  }

  // epilogue: O /= l, write Y[b][t][h*64+d]
#pragma unroll
  for (int mi = 0; mi < 2; ++mi)
#pragma unroll
    for (int r = 0; r < 4; ++r) {
      float rl = 1.0f / lr[mi][r];
      int t = qw + mi * 16 + l4 * 4 + r;
#pragma unroll
      for (int di = 0; di < 4; ++di) {
        float ov = o[mi][di][r] * rl;
        int c = h * 64 + di * 16 + l15;
        Y[((u64)(b2 * T_ + t)) * C_ + c] = f2bf(ov);
      }
    }
}

// ---------- launcher ----------
extern "C" void kernel_launch(void* const* d_in, const int* in_sizes, int n_in,
                              void* d_out, int out_size, void* d_ws, size_t ws_size,
                              hipStream_t stream) {
  (void)in_sizes; (void)n_in; (void)out_size; (void)ws_size;
  const float* x = (const float*)d_in[0];
  const float* w_attn = (const float*)d_in[1];
  const float* w_proj = (const float*)d_in[2];
  float* out = (float*)d_out;

  u16* xb = (u16*)d_ws;                       // [4096][1024] bf16 (reused as Y)
  u16* waT = xb + (u64)M_ * C_;               // [3072][1024]
  u16* wpT = waT + (u64)3 * C_ * C_;          // [1024][1024]
  u16* qb = wpT + (u64)C_ * C_;               // [BH][T][64]
  u16* kb = qb + (u64)BH_ * T_ * HD_;
  u16* vb = kb + (u64)BH_ * T_ * HD_;
  u16* vt = vb + (u64)BH_ * T_ * HD_;
  float* ct = (float*)(vt + (u64)BH_ * T_ * HD_);
  float* st = ct + T_ * 32;
  u16* yb = xb;                               // reuse xb after GEMM1

  rope_table_k<<<256, 256, 0, stream>>>(ct, st);
  cvt_f32_bf16_k<<<(M_ * C_ / 8) / 256, 256, 0, stream>>>(x, xb);
  transpose_w_k<<<dim3(48, 16), 256, 0, stream>>>(w_attn, waT, 3 * C_, C_);
  transpose_w_k<<<dim3(16, 16), 256, 0, stream>>>(w_proj, wpT, C_, C_);

  gemm_bt_k<1><<<dim3(24, 32), 256, 0, stream>>>(xb, waT, nullptr, qb, kb, vb,
                                                 M_, 3 * C_, C_);

  rope_apply_k<<<(BH_ * T_ * 4) / 256, 256, 0, stream>>>(qb, ct, st);
  rope_apply_k<<<(BH_ * T_ * 4) / 256, 256, 0, stream>>>(kb, ct, st);
  transpose_v_k<<<dim3(32, 32), 256, 0, stream>>>(vb, vt);

  attn_fwd_k<<<dim3(16, 32), 256, 0, stream>>>(qb, kb, vt, yb);

  gemm_bt_k<0><<<dim3(8, 32), 256, 0, stream>>>(yb, wpT, out, nullptr, nullptr,
                                                nullptr, M_, C_, C_);
}

// Round 2
// 163.187 us; speedup vs baseline: 1.4902x; 1.4902x over previous
//
#include <hip/hip_runtime.h>

typedef unsigned short u16;
typedef unsigned int u32;
typedef unsigned long long u64;
typedef __attribute__((ext_vector_type(8))) short s16x8;
typedef __attribute__((ext_vector_type(8))) __bf16 bf16x8;
typedef __attribute__((ext_vector_type(4))) float fx4;
typedef __attribute__((ext_vector_type(16))) float fx16;
typedef __attribute__((ext_vector_type(2))) u32 u32x2;
typedef __attribute__((ext_vector_type(4))) u32 u32x4;

// ---------- helpers ----------
__device__ __forceinline__ fx4 mfma_16x16x32(s16x8 a, s16x8 b, fx4 c) {
  return __builtin_amdgcn_mfma_f32_16x16x32_bf16(
      __builtin_bit_cast(bf16x8, a), __builtin_bit_cast(bf16x8, b), c, 0, 0, 0);
}
__device__ __forceinline__ fx16 mfma_32x32x16(s16x8 a, s16x8 b, fx16 c) {
  return __builtin_amdgcn_mfma_f32_32x32x16_bf16(
      __builtin_bit_cast(bf16x8, a), __builtin_bit_cast(bf16x8, b), c, 0, 0, 0);
}

__device__ __forceinline__ u16 f2bf(float f) {
  u32 u = __builtin_bit_cast(u32, f);
  u32 r = u + 0x7fffu + ((u >> 16) & 1u);
  return (u16)(r >> 16);
}
__device__ __forceinline__ float bf2f(u16 h) {
  u32 u = ((u32)h) << 16;
  return __builtin_bit_cast(float, u);
}

__device__ __forceinline__ u32 cvtpk(float lo, float hi) {
  u32 r;
  asm("v_cvt_pk_bf16_f32 %0, %1, %2" : "=v"(r) : "v"(lo), "v"(hi));
  return r;
}

__device__ __forceinline__ void plswap(u32& x, u32& y) {
  typedef __attribute__((ext_vector_type(2))) unsigned int uix2;
  uix2 r = __builtin_amdgcn_permlane32_swap(x, y, false, false);
  x = r[0];
  y = r[1];
}

// cross-half (lane i <-> lane i+32) combine: returns max/sum over both halves
__device__ __forceinline__ float xhalf_max(float v) {
  u32 a = __builtin_bit_cast(u32, v), b = a;
  plswap(a, b);  // a = low-half values (both halves), b = high-half values
  return fmaxf(__builtin_bit_cast(float, a), __builtin_bit_cast(float, b));
}
__device__ __forceinline__ float xhalf_sum(float v) {
  u32 a = __builtin_bit_cast(u32, v), b = a;
  plswap(a, b);
  return __builtin_bit_cast(float, a) + __builtin_bit_cast(float, b);
}

__device__ __forceinline__ void gload16(const void* g, void* l) {
  __builtin_amdgcn_global_load_lds(
      (const __attribute__((address_space(1))) u32*)g,
      (__attribute__((address_space(3))) u32*)l, 16, 0, 0);
}

// ---------- constants ----------
#define B_ 2
#define T_ 2048
#define C_ 1024
#define H_ 16
#define HD_ 64
#define BH_ 32
#define M_ 4096   // B*T
// (1/sqrt(64)) * log2(e), folded into Q at RoPE time
#define CF_ 0.18033688011112042f

// ---------- prep kernels ----------
__global__ void rope_table_k(float* __restrict__ ct, float* __restrict__ st) {
  int id = blockIdx.x * 256 + threadIdx.x;  // 65536 = T*32
  int t = id >> 5, i = id & 31;
  float f = exp2f(-(float)i * (13.287712379549449f / 32.0f));
  float a = (float)t * f;
  float s, c;
  sincosf(a, &s, &c);
  ct[id] = c;
  st[id] = s;
}

__global__ void cvt_f32_bf16_k(const float* __restrict__ in, u16* __restrict__ outp) {
  int id = blockIdx.x * 256 + threadIdx.x;
  const fx4* p = (const fx4*)(in + (u64)id * 8);
  fx4 v0 = p[0], v1 = p[1];
  s16x8 r;
#pragma unroll
  for (int j = 0; j < 4; ++j) {
    r[j] = (short)f2bf(v0[j]);
    r[4 + j] = (short)f2bf(v1[j]);
  }
  *((s16x8*)outp + id) = r;
}

// W [R][Ncols] f32  ->  WT [Ncols][R] bf16
__global__ void transpose_w_k(const float* __restrict__ W, u16* __restrict__ WT,
                              int Ncols, int R) {
  __shared__ u16 T_s[64 * 72];
  int c0 = blockIdx.x * 64, r0 = blockIdx.y * 64;
  int tid = threadIdx.x;
#pragma unroll
  for (int it = 0; it < 4; ++it) {
    int idx = it * 256 + tid;
    int r = idx >> 4, c4 = (idx & 15) * 4;
    fx4 v = *(const fx4*)(W + (u64)(r0 + r) * Ncols + c0 + c4);
#pragma unroll
    for (int j = 0; j < 4; ++j) T_s[(c4 + j) * 72 + r] = f2bf(v[j]);
  }
  __syncthreads();
#pragma unroll
  for (int it = 0; it < 2; ++it) {
    int idx = it * 256 + tid;
    int rc = idx >> 3, c8 = (idx & 7) * 8;
    s16x8 v = *(const s16x8*)(T_s + rc * 72 + c8);
    *(s16x8*)(WT + (u64)(c0 + rc) * R + r0 + c8) = v;
  }
}

// in-place RoPE on blocked layout P [bh][8 dblocks][T][8], pairs (db, db+4).
// scale folded into output (CF_ for Q, 1.0 for K).
__global__ void rope_blocked_k(u16* __restrict__ P, const float* __restrict__ ct,
                               const float* __restrict__ st, float scale) {
  int id = blockIdx.x * 256 + threadIdx.x;  // 32*4*2048 = 262144
  int bh = id >> 13;
  int q = (id >> 11) & 3;
  int t = id & (T_ - 1);
  u16* plo = P + (((u64)bh * 8 + q) * T_ + t) * 8;
  u16* phi = plo + (u64)4 * T_ * 8;
  s16x8 lo = *(const s16x8*)plo, hi = *(const s16x8*)phi;
  s16x8 olo, ohi;
#pragma unroll
  for (int j = 0; j < 8; ++j) {
    float c = ct[t * 32 + q * 8 + j];
    float s = st[t * 32 + q * 8 + j];
    float l = bf2f((u16)lo[j]), h = bf2f((u16)hi[j]);
    olo[j] = (short)f2bf((l * c - h * s) * scale);
    ohi[j] = (short)f2bf((h * c + l * s) * scale);
  }
  *(s16x8*)plo = olo;
  *(s16x8*)phi = ohi;
}

// ---------- GEMM: A[M][K] bf16 @ B[N][K]^T bf16, 128x128 tile ----------
// EPI==0: C fp32 [M][N].
// EPI==1: scatter to blocked Qp/Kp [bh][8][T][8] and Vp [bh][T/8][64][8].
template <int EPI>
__global__ __launch_bounds__(256, 2) void gemm_bt_k(
    const u16* __restrict__ A, const u16* __restrict__ B, float* __restrict__ C,
    u16* __restrict__ Qo, u16* __restrict__ Ko, u16* __restrict__ Vo,
    int M, int N, int K) {
  __shared__ u16 As[128 * 32];
  __shared__ u16 Bs[128 * 32];
  int tid = threadIdx.x, lane = tid & 63, w = tid >> 6;
  int wm = w >> 1, wn = w & 1, l15 = lane & 15, l4 = lane >> 4;
  int m0 = blockIdx.y * 128, n0 = blockIdx.x * 128;
  fx4 acc[4][4] = {};
  int arow = tid >> 2, ac8 = (tid & 3) * 8;
  const u16* Ab = A + (u64)(m0 + arow) * K + ac8;
  const u16* Bb = B + (u64)(n0 + arow) * K + ac8;
  char* AsB = (char*)As + tid * 16;
  char* BsB = (char*)Bs + tid * 16;

  for (int k0 = 0; k0 < K; k0 += 32) {
    __syncthreads();
    gload16(Ab + k0, AsB);
    gload16(Ab + (u64)64 * K + k0, AsB + 4096);
    gload16(Bb + k0, BsB);
    gload16(Bb + (u64)64 * K + k0, BsB + 4096);
    __syncthreads();
    s16x8 a[4], b[4];
#pragma unroll
    for (int mi = 0; mi < 4; ++mi)
      a[mi] = *(const s16x8*)((const char*)As + (wm * 64 + mi * 16 + l15) * 64 + l4 * 16);
#pragma unroll
    for (int ni = 0; ni < 4; ++ni)
      b[ni] = *(const s16x8*)((const char*)Bs + (wn * 64 + ni * 16 + l15) * 64 + l4 * 16);
#pragma unroll
    for (int mi = 0; mi < 4; ++mi)
#pragma unroll
      for (int ni = 0; ni < 4; ++ni)
        acc[mi][ni] = mfma_16x16x32(a[mi], b[ni], acc[mi][ni]);
  }

  if (EPI == 0) {
#pragma unroll
    for (int mi = 0; mi < 4; ++mi)
#pragma unroll
      for (int ni = 0; ni < 4; ++ni)
#pragma unroll
        for (int r = 0; r < 4; ++r) {
          u64 row = (u64)(m0 + wm * 64 + mi * 16 + l4 * 4 + r);
          int col = n0 + wn * 64 + ni * 16 + l15;
          C[row * N + col] = acc[mi][ni][r];
        }
  } else {
#pragma unroll
    for (int mi = 0; mi < 4; ++mi)
#pragma unroll
      for (int ni = 0; ni < 4; ++ni)
#pragma unroll
        for (int r = 0; r < 4; ++r) {
          int row = m0 + wm * 64 + mi * 16 + l4 * 4 + r;
          int col = n0 + wn * 64 + ni * 16 + l15;
          int b2 = row >> 11, t = row & (T_ - 1);
          int qi = col >> 10, h = (col >> 6) & 15, d = col & 63;
          u16 val = f2bf(acc[mi][ni][r]);
          if (qi == 2) {
            Vo[((((u64)(b2 * H_ + h)) * (T_ / 8) + (t >> 3)) * HD_ + d) * 8 + (t & 7)] = val;
          } else {
            u16* dst = (qi == 0 ? Qo : Ko);
            dst[((((u64)(b2 * H_ + h)) * 8 + (d >> 3)) * T_ + t) * 8 + (d & 7)] = val;
          }
        }
  }
}

// ---------- flash attention, swapped-QK^T, per-wave, no LDS ----------
// Qp,Kp [bh][8 dblocks][T][8] bf16 (RoPE'd; Q pre-scaled by CF_)
// Vp [bh][T/8 kblocks][64 d][8 keys] bf16
// Y [B][T][C] bf16
__global__ __launch_bounds__(256, 2) void attn_fwd_k(
    const u16* __restrict__ Qp, const u16* __restrict__ Kp,
    const u16* __restrict__ Vp, u16* __restrict__ Y) {
  int tid = threadIdx.x, lane = tid & 63, w = tid >> 6;
  int ql = lane & 31, h = lane >> 5;
  int bh = blockIdx.x & 31;
  int bgrp = blockIdx.x >> 5;          // 0..15
  int j = w * 16 + bgrp;               // q-tile 0..63 (balanced across waves)
  int q0 = j * 32;
  int b2 = bh >> 4, head = bh & 15;

  // Q fragments (B-operand): row=q=lane&31, k = h*8+j within each 16-d step
  s16x8 qf[4];
#pragma unroll
  for (int ks = 0; ks < 4; ++ks)
    qf[ks] = *(const s16x8*)(Qp + (((u64)bh * 8 + ks * 2 + h) * T_ + q0 + ql) * 8);

  // K fragment base pointers (A-operand): row=key=lane&31
  const u16* kp[4];
#pragma unroll
  for (int ks = 0; ks < 4; ++ks)
    kp[ks] = Kp + (((u64)bh * 8 + ks * 2 + h) * T_ + ql) * 8;
  // V fragment base (A-operand): row=d
  const u16* vpb = Vp + (((u64)bh * (T_ / 8) + h) * HD_ + ql) * 8;

  fx16 oL = {}, oH = {};
  float m = -1e30f, l = 0.f;

  for (int kv = 0; kv <= j; ++kv) {
    // ---- S^T = K Q^T (lane: q=lane&31; reg r: key = kv*32 + (r&3)+8*(r>>2)+4h)
    fx16 s = {};
#pragma unroll
    for (int ks = 0; ks < 4; ++ks) {
      s16x8 kf = *(const s16x8*)(kp[ks] + (u64)kv * 256);
      s = mfma_32x32x16(kf, qf[ks], s);
    }
    if (kv == j) {  // causal mask (wave-uniform branch)
#pragma unroll
      for (int r = 0; r < 16; ++r) {
        int cr = (r & 3) + 8 * (r >> 2) + 4 * h;
        s[r] = (cr > ql) ? -1e30f : s[r];
      }
    }
    // ---- online softmax (values already in exp2 domain via Q pre-scale)
    float t0 = fmaxf(s[0], s[8]), t1 = fmaxf(s[1], s[9]);
    float t2 = fmaxf(s[2], s[10]), t3 = fmaxf(s[3], s[11]);
    float t4 = fmaxf(s[4], s[12]), t5 = fmaxf(s[5], s[13]);
    float t6 = fmaxf(s[6], s[14]), t7 = fmaxf(s[7], s[15]);
    t0 = fmaxf(t0, t4); t1 = fmaxf(t1, t5); t2 = fmaxf(t2, t6); t3 = fmaxf(t3, t7);
    t0 = fmaxf(t0, t2); t1 = fmaxf(t1, t3);
    float rowmax = xhalf_max(fmaxf(t0, t1));
    if (!__all(rowmax <= m + 8.f)) {  // T13 defer-max
      float mnew = fmaxf(m, rowmax);
      float corr = exp2f(m - mnew);
      l *= corr;
      oL *= corr;
      oH *= corr;
      m = mnew;
    }
    float p[16];
#pragma unroll
    for (int r = 0; r < 16; ++r) p[r] = exp2f(s[r] - m);
    float a0 = (p[0] + p[8]) + (p[1] + p[9]);
    float a1 = (p[2] + p[10]) + (p[3] + p[11]);
    float a2 = (p[4] + p[12]) + (p[5] + p[13]);
    float a3 = (p[6] + p[14]) + (p[7] + p[15]);
    l += xhalf_sum((a0 + a1) + (a2 + a3));
    // ---- repack P -> bf16 B-fragments (keys h*8+0..7 per 16-key step)
    u32 x0 = cvtpk(p[0], p[1]), x1 = cvtpk(p[2], p[3]);
    u32 y0 = cvtpk(p[4], p[5]), y1 = cvtpk(p[6], p[7]);
    plswap(x0, y0);
    plswap(x1, y1);
    u32x4 f0w = {x0, x1, y0, y1};
    u32 x2 = cvtpk(p[8], p[9]), x3 = cvtpk(p[10], p[11]);
    u32 y2 = cvtpk(p[12], p[13]), y3 = cvtpk(p[14], p[15]);
    plswap(x2, y2);
    plswap(x3, y3);
    u32x4 f1w = {x2, x3, y2, y3};
    s16x8 pf0 = __builtin_bit_cast(s16x8, f0w);
    s16x8 pf1 = __builtin_bit_cast(s16x8, f1w);
    // ---- O^T += V^T P  (lane: q=lane&31; reg r: d = (r&3)+8*(r>>2)+4h [+32])
    const u16* vk = vpb + (u64)kv * 2048;
    s16x8 v00 = *(const s16x8*)(vk);
    s16x8 v01 = *(const s16x8*)(vk + 256);
    s16x8 v10 = *(const s16x8*)(vk + 1024);
    s16x8 v11 = *(const s16x8*)(vk + 1280);
    oL = mfma_32x32x16(v00, pf0, oL);
    oH = mfma_32x32x16(v01, pf0, oH);
    oL = mfma_32x32x16(v10, pf1, oL);
    oH = mfma_32x32x16(v11, pf1, oH);
  }

  // ---- epilogue: Y[b][t][head*64+d] = O/l
  float rl = 1.0f / l;
  int t = q0 + ql;
  u64 ybase = ((u64)(b2 * T_ + t)) * C_ + head * HD_;
#pragma unroll
  for (int g = 0; g < 4; ++g) {
    u32x2 s2;
    s2[0] = cvtpk(oL[4 * g] * rl, oL[4 * g + 1] * rl);
    s2[1] = cvtpk(oL[4 * g + 2] * rl, oL[4 * g + 3] * rl);
    *(u32x2*)(Y + ybase + g * 8 + h * 4) = s2;
    u32x2 s3;
    s3[0] = cvtpk(oH[4 * g] * rl, oH[4 * g + 1] * rl);
    s3[1] = cvtpk(oH[4 * g + 2] * rl, oH[4 * g + 3] * rl);
    *(u32x2*)(Y + ybase + 32 + g * 8 + h * 4) = s3;
  }
}

// ---------- launcher ----------
extern "C" void kernel_launch(void* const* d_in, const int* in_sizes, int n_in,
                              void* d_out, int out_size, void* d_ws, size_t ws_size,
                              hipStream_t stream) {
  (void)in_sizes; (void)n_in; (void)out_size; (void)ws_size;
  const float* x = (const float*)d_in[0];
  const float* w_attn = (const float*)d_in[1];
  const float* w_proj = (const float*)d_in[2];
  float* out = (float*)d_out;

  u16* xb = (u16*)d_ws;                       // [4096][1024] bf16 (reused as Y)
  u16* waT = xb + (u64)M_ * C_;               // [3072][1024]
  u16* wpT = waT + (u64)3 * C_ * C_;          // [1024][1024]
  u16* Qp = wpT + (u64)C_ * C_;               // [32][8][2048][8]
  u16* Kp = Qp + (u64)BH_ * T_ * HD_;
  u16* Vp = Kp + (u64)BH_ * T_ * HD_;         // [32][256][64][8]
  float* ct = (float*)(Vp + (u64)BH_ * T_ * HD_);
  float* st = ct + T_ * 32;
  u16* yb = xb;                               // reuse xb after GEMM1

  rope_table_k<<<256, 256, 0, stream>>>(ct, st);
  cvt_f32_bf16_k<<<(M_ * C_ / 8) / 256, 256, 0, stream>>>(x, xb);
  transpose_w_k<<<dim3(48, 16), 256, 0, stream>>>(w_attn, waT, 3 * C_, C_);
  transpose_w_k<<<dim3(16, 16), 256, 0, stream>>>(w_proj, wpT, C_, C_);

  gemm_bt_k<1><<<dim3(24, 32), 256, 0, stream>>>(xb, waT, nullptr, Qp, Kp, Vp,
                                                 M_, 3 * C_, C_);

  rope_blocked_k<<<1024, 256, 0, stream>>>(Qp, ct, st, CF_);
  rope_blocked_k<<<1024, 256, 0, stream>>>(Kp, ct, st, 1.0f);

  attn_fwd_k<<<512, 256, 0, stream>>>(Qp, Kp, Vp, yb);

  gemm_bt_k<0><<<dim3(8, 32), 256, 0, stream>>>(yb, wpT, out, nullptr, nullptr,
                                                nullptr, M_, C_, C_);
}

// Round 3
// 144.040 us; speedup vs baseline: 1.6882x; 1.1329x over previous
//
#include <hip/hip_runtime.h>

typedef unsigned short u16;
typedef unsigned int u32;
typedef unsigned long long u64;
typedef __attribute__((ext_vector_type(8))) short s16x8;
typedef __attribute__((ext_vector_type(8))) __bf16 bf16x8;
typedef __attribute__((ext_vector_type(4))) float fx4;
typedef __attribute__((ext_vector_type(16))) float fx16;
typedef __attribute__((ext_vector_type(2))) u32 u32x2;
typedef __attribute__((ext_vector_type(4))) u32 u32x4;

// ---------- helpers ----------
__device__ __forceinline__ fx4 mfma_16x16x32(s16x8 a, s16x8 b, fx4 c) {
  return __builtin_amdgcn_mfma_f32_16x16x32_bf16(
      __builtin_bit_cast(bf16x8, a), __builtin_bit_cast(bf16x8, b), c, 0, 0, 0);
}
__device__ __forceinline__ fx16 mfma_32x32x16(s16x8 a, s16x8 b, fx16 c) {
  return __builtin_amdgcn_mfma_f32_32x32x16_bf16(
      __builtin_bit_cast(bf16x8, a), __builtin_bit_cast(bf16x8, b), c, 0, 0, 0);
}

__device__ __forceinline__ u16 f2bf(float f) {
  u32 u = __builtin_bit_cast(u32, f);
  u32 r = u + 0x7fffu + ((u >> 16) & 1u);
  return (u16)(r >> 16);
}
__device__ __forceinline__ float bf2f(u16 h) {
  u32 u = ((u32)h) << 16;
  return __builtin_bit_cast(float, u);
}

__device__ __forceinline__ u32 cvtpk(float lo, float hi) {
  u32 r;
  asm("v_cvt_pk_bf16_f32 %0, %1, %2" : "=v"(r) : "v"(lo), "v"(hi));
  return r;
}

__device__ __forceinline__ void plswap(u32& x, u32& y) {
  typedef __attribute__((ext_vector_type(2))) unsigned int uix2;
  uix2 r = __builtin_amdgcn_permlane32_swap(x, y, false, false);
  x = r[0];
  y = r[1];
}

__device__ __forceinline__ float xhalf_max(float v) {
  u32 a = __builtin_bit_cast(u32, v), b = a;
  plswap(a, b);
  return fmaxf(__builtin_bit_cast(float, a), __builtin_bit_cast(float, b));
}
__device__ __forceinline__ float xhalf_sum(float v) {
  u32 a = __builtin_bit_cast(u32, v), b = a;
  plswap(a, b);
  return __builtin_bit_cast(float, a) + __builtin_bit_cast(float, b);
}

__device__ __forceinline__ void gload16(const void* g, void* l) {
  __builtin_amdgcn_global_load_lds(
      (const __attribute__((address_space(1))) u32*)g,
      (__attribute__((address_space(3))) u32*)l, 16, 0, 0);
}

// ---------- constants ----------
#define B_ 2
#define T_ 2048
#define C_ 1024
#define H_ 16
#define HD_ 64
#define BH_ 32
#define M_ 4096   // B*T
// (1/sqrt(64)) * log2(e), folded into Q at GEMM1 epilogue (fused RoPE)
#define CF_ 0.18033688011112042f

// ---------- prep kernels ----------
__global__ void rope_table_k(float* __restrict__ ct, float* __restrict__ st) {
  int id = blockIdx.x * 256 + threadIdx.x;  // 65536 = T*32
  int t = id >> 5, i = id & 31;
  float f = exp2f(-(float)i * (13.287712379549449f / 32.0f));
  float a = (float)t * f;
  float s, c;
  sincosf(a, &s, &c);
  ct[id] = c;
  st[id] = s;
}

__global__ void cvt_f32_bf16_k(const float* __restrict__ in, u16* __restrict__ outp) {
  int id = blockIdx.x * 256 + threadIdx.x;
  const fx4* p = (const fx4*)(in + (u64)id * 8);
  fx4 v0 = p[0], v1 = p[1];
  s16x8 r;
#pragma unroll
  for (int j = 0; j < 4; ++j) {
    r[j] = (short)f2bf(v0[j]);
    r[4 + j] = (short)f2bf(v1[j]);
  }
  *((s16x8*)outp + id) = r;
}

// W [R][Ncols] f32  ->  WT [Ncols][R] bf16
__global__ void transpose_w_k(const float* __restrict__ W, u16* __restrict__ WT,
                              int Ncols, int R) {
  __shared__ u16 T_s[64 * 72];
  int c0 = blockIdx.x * 64, r0 = blockIdx.y * 64;
  int tid = threadIdx.x;
#pragma unroll
  for (int it = 0; it < 4; ++it) {
    int idx = it * 256 + tid;
    int r = idx >> 4, c4 = (idx & 15) * 4;
    fx4 v = *(const fx4*)(W + (u64)(r0 + r) * Ncols + c0 + c4);
#pragma unroll
    for (int j = 0; j < 4; ++j) T_s[(c4 + j) * 72 + r] = f2bf(v[j]);
  }
  __syncthreads();
#pragma unroll
  for (int it = 0; it < 2; ++it) {
    int idx = it * 256 + tid;
    int rc = idx >> 3, c8 = (idx & 7) * 8;
    s16x8 v = *(const s16x8*)(T_s + rc * 72 + c8);
    *(s16x8*)(WT + (u64)(c0 + rc) * R + r0 + c8) = v;
  }
}

// ---------- GEMM: A[M][K] bf16 @ B[N][K]^T bf16, 128x128 tile ----------
// EPI==0: C fp32 [M][N].
// EPI==1: fused RoPE epilogue, scatter to blocked Qp/Kp [bh][8][T][8]
//         (Q scaled by CF_) and Vp [bh][T/8][64][8].
template <int EPI>
__global__ __launch_bounds__(256, 2) void gemm_bt_k(
    const u16* __restrict__ A, const u16* __restrict__ B, float* __restrict__ C,
    u16* __restrict__ Qo, u16* __restrict__ Ko, u16* __restrict__ Vo,
    const float* __restrict__ ct, const float* __restrict__ st,
    int M, int N, int K) {
  __shared__ u16 As[128 * 32];
  __shared__ u16 Bs[128 * 32];
  int tid = threadIdx.x, lane = tid & 63, w = tid >> 6;
  int wm = w >> 1, wn = w & 1, l15 = lane & 15, l4 = lane >> 4;
  int m0 = blockIdx.y * 128, n0 = blockIdx.x * 128;
  fx4 acc[4][4] = {};
  int arow = tid >> 2, ac8 = (tid & 3) * 8;
  const u16* Ab = A + (u64)(m0 + arow) * K + ac8;
  const u16* Bb = B + (u64)(n0 + arow) * K + ac8;
  char* AsB = (char*)As + tid * 16;
  char* BsB = (char*)Bs + tid * 16;

  for (int k0 = 0; k0 < K; k0 += 32) {
    __syncthreads();
    gload16(Ab + k0, AsB);
    gload16(Ab + (u64)64 * K + k0, AsB + 4096);
    gload16(Bb + k0, BsB);
    gload16(Bb + (u64)64 * K + k0, BsB + 4096);
    __syncthreads();
    s16x8 a[4], b[4];
#pragma unroll
    for (int mi = 0; mi < 4; ++mi)
      a[mi] = *(const s16x8*)((const char*)As + (wm * 64 + mi * 16 + l15) * 64 + l4 * 16);
#pragma unroll
    for (int ni = 0; ni < 4; ++ni)
      b[ni] = *(const s16x8*)((const char*)Bs + (wn * 64 + ni * 16 + l15) * 64 + l4 * 16);
#pragma unroll
    for (int mi = 0; mi < 4; ++mi)
#pragma unroll
      for (int ni = 0; ni < 4; ++ni)
        acc[mi][ni] = mfma_16x16x32(a[mi], b[ni], acc[mi][ni]);
  }

  if (EPI == 0) {
#pragma unroll
    for (int mi = 0; mi < 4; ++mi)
#pragma unroll
      for (int ni = 0; ni < 4; ++ni)
#pragma unroll
        for (int r = 0; r < 4; ++r) {
          u64 row = (u64)(m0 + wm * 64 + mi * 16 + l4 * 4 + r);
          int col = n0 + wn * 64 + ni * 16 + l15;
          C[row * N + col] = acc[mi][ni][r];
        }
  } else {
#pragma unroll
    for (int mi = 0; mi < 4; ++mi)
#pragma unroll
      for (int r = 0; r < 4; ++r) {
        int row = m0 + wm * 64 + mi * 16 + l4 * 4 + r;
        int b2 = row >> 11, t = row & (T_ - 1);
#pragma unroll
        for (int ni = 0; ni < 2; ++ni) {
          int col = n0 + wn * 64 + ni * 16 + l15;
          int qi = col >> 10, h = (col >> 6) & 15, d = ni * 16 + l15;  // d in 0..31
          float lo = acc[mi][ni][r], hi = acc[mi][ni + 2][r];
          if (qi == 2) {
            u64 vbase =
                ((((u64)(b2 * H_ + h)) * (T_ / 8) + (t >> 3)) * HD_ + d) * 8 + (t & 7);
            Vo[vbase] = f2bf(lo);
            Vo[vbase + 32 * 8] = f2bf(hi);
          } else {
            float c = ct[t * 32 + d], s = st[t * 32 + d];
            float sc = (qi == 0) ? CF_ : 1.0f;
            u16* dst = (qi == 0) ? Qo : Ko;
            u64 base = ((((u64)(b2 * H_ + h)) * 8 + (d >> 3)) * T_ + t) * 8 + (d & 7);
            dst[base] = f2bf((lo * c - hi * s) * sc);
            dst[base + (u64)4 * T_ * 8] = f2bf((hi * c + lo * s) * sc);
          }
        }
      }
  }
}

// ---------- flash attention, swapped-QK^T, 1 wave per block, reg prefetch ----
// Qp,Kp [bh][8 dblocks][T][8] bf16 (RoPE'd; Q pre-scaled by CF_)
// Vp [bh][T/8 kblocks][64 d][8 keys] bf16
// Y [B][T][C] bf16

#define ATTN_LOAD(KC, VC, KVI)                                         \
  do {                                                                 \
    _Pragma("unroll")                                                  \
    for (int ks_ = 0; ks_ < 4; ++ks_)                                  \
      KC[ks_] = *(const s16x8*)(kp[ks_] + (u64)(KVI) * 256);           \
    const u16* vk_ = vpb + (u64)(KVI) * 2048;                          \
    VC[0] = *(const s16x8*)(vk_);                                      \
    VC[1] = *(const s16x8*)(vk_ + 256);                                \
    VC[2] = *(const s16x8*)(vk_ + 1024);                               \
    VC[3] = *(const s16x8*)(vk_ + 1280);                               \
  } while (0)

#define ATTN_BODY(KC, VC, KVI)                                                \
  do {                                                                        \
    fx16 s = {};                                                              \
    _Pragma("unroll")                                                         \
    for (int ks_ = 0; ks_ < 4; ++ks_) s = mfma_32x32x16(KC[ks_], qf[ks_], s); \
    if ((KVI) == j) {                                                         \
      _Pragma("unroll")                                                       \
      for (int r_ = 0; r_ < 16; ++r_) {                                       \
        int cr_ = (r_ & 3) + 8 * (r_ >> 2) + 4 * h;                           \
        s[r_] = (cr_ > ql) ? -1e30f : s[r_];                                  \
      }                                                                       \
    }                                                                         \
    float t0_ = fmaxf(s[0], s[8]), t1_ = fmaxf(s[1], s[9]);                   \
    float t2_ = fmaxf(s[2], s[10]), t3_ = fmaxf(s[3], s[11]);                 \
    float t4_ = fmaxf(s[4], s[12]), t5_ = fmaxf(s[5], s[13]);                 \
    float t6_ = fmaxf(s[6], s[14]), t7_ = fmaxf(s[7], s[15]);                 \
    t0_ = fmaxf(t0_, t4_); t1_ = fmaxf(t1_, t5_);                             \
    t2_ = fmaxf(t2_, t6_); t3_ = fmaxf(t3_, t7_);                             \
    t0_ = fmaxf(t0_, t2_); t1_ = fmaxf(t1_, t3_);                             \
    float rowmax_ = xhalf_max(fmaxf(t0_, t1_));                               \
    if (!__all(rowmax_ <= m + 8.f)) {                                         \
      float mnew_ = fmaxf(m, rowmax_);                                        \
      float corr_ = exp2f(m - mnew_);                                         \
      l *= corr_;                                                             \
      oL *= corr_;                                                            \
      oH *= corr_;                                                            \
      m = mnew_;                                                              \
    }                                                                         \
    float p_[16];                                                             \
    _Pragma("unroll")                                                         \
    for (int r_ = 0; r_ < 16; ++r_) p_[r_] = exp2f(s[r_] - m);                \
    float a0_ = (p_[0] + p_[8]) + (p_[1] + p_[9]);                            \
    float a1_ = (p_[2] + p_[10]) + (p_[3] + p_[11]);                          \
    float a2_ = (p_[4] + p_[12]) + (p_[5] + p_[13]);                          \
    float a3_ = (p_[6] + p_[14]) + (p_[7] + p_[15]);                          \
    l += xhalf_sum((a0_ + a1_) + (a2_ + a3_));                                \
    u32 x0_ = cvtpk(p_[0], p_[1]), x1_ = cvtpk(p_[2], p_[3]);                 \
    u32 y0_ = cvtpk(p_[4], p_[5]), y1_ = cvtpk(p_[6], p_[7]);                 \
    plswap(x0_, y0_);                                                         \
    plswap(x1_, y1_);                                                         \
    u32x4 f0w_ = {x0_, x1_, y0_, y1_};                                        \
    u32 x2_ = cvtpk(p_[8], p_[9]), x3_ = cvtpk(p_[10], p_[11]);               \
    u32 y2_ = cvtpk(p_[12], p_[13]), y3_ = cvtpk(p_[14], p_[15]);             \
    plswap(x2_, y2_);                                                         \
    plswap(x3_, y3_);                                                         \
    u32x4 f1w_ = {x2_, x3_, y2_, y3_};                                        \
    s16x8 pf0_ = __builtin_bit_cast(s16x8, f0w_);                             \
    s16x8 pf1_ = __builtin_bit_cast(s16x8, f1w_);                             \
    oL = mfma_32x32x16(VC[0], pf0_, oL);                                      \
    oH = mfma_32x32x16(VC[1], pf0_, oH);                                      \
    oL = mfma_32x32x16(VC[2], pf1_, oL);                                      \
    oH = mfma_32x32x16(VC[3], pf1_, oH);                                      \
  } while (0)

__global__ __launch_bounds__(64, 2) void attn_fwd_k(
    const u16* __restrict__ Qp, const u16* __restrict__ Kp,
    const u16* __restrict__ Vp, u16* __restrict__ Y) {
  int lane = threadIdx.x;
  int ql = lane & 31, h = lane >> 5;
  int bh = blockIdx.x & 31;
  int half = blockIdx.x >> 10;           // 0: j=63..32 (long first), 1: j=0..31
  int pq = (blockIdx.x >> 5) & 31;
  int j = half ? pq : 63 - pq;
  int q0 = j * 32;
  int b2 = bh >> 4, head = bh & 15;

  // Q fragments (B-operand): row=q=lane&31, k = h*8+i within each 16-d step
  s16x8 qf[4];
#pragma unroll
  for (int ks = 0; ks < 4; ++ks)
    qf[ks] = *(const s16x8*)(Qp + (((u64)bh * 8 + ks * 2 + h) * T_ + q0 + ql) * 8);

  const u16* kp[4];
#pragma unroll
  for (int ks = 0; ks < 4; ++ks)
    kp[ks] = Kp + (((u64)bh * 8 + ks * 2 + h) * T_ + ql) * 8;
  const u16* vpb = Vp + (((u64)bh * (T_ / 8) + h) * HD_ + ql) * 8;

  fx16 oL = {}, oH = {};
  float m = -1e30f, l = 0.f;

  s16x8 kA[4], vA[4], kB[4], vB[4];
  ATTN_LOAD(kA, vA, 0);
  int kv = 0;
  for (; kv + 1 <= j; kv += 2) {
    ATTN_LOAD(kB, vB, kv + 1);
    ATTN_BODY(kA, vA, kv);
    if (kv + 2 <= j) ATTN_LOAD(kA, vA, kv + 2);
    ATTN_BODY(kB, vB, kv + 1);
  }
  if (kv <= j) ATTN_BODY(kA, vA, kv);

  // ---- epilogue: Y[b][t][head*64+d] = O/l
  float rl = 1.0f / l;
  int t = q0 + ql;
  u64 ybase = ((u64)(b2 * T_ + t)) * C_ + head * HD_;
#pragma unroll
  for (int g = 0; g < 4; ++g) {
    u32x2 s2;
    s2[0] = cvtpk(oL[4 * g] * rl, oL[4 * g + 1] * rl);
    s2[1] = cvtpk(oL[4 * g + 2] * rl, oL[4 * g + 3] * rl);
    *(u32x2*)(Y + ybase + g * 8 + h * 4) = s2;
    u32x2 s3;
    s3[0] = cvtpk(oH[4 * g] * rl, oH[4 * g + 1] * rl);
    s3[1] = cvtpk(oH[4 * g + 2] * rl, oH[4 * g + 3] * rl);
    *(u32x2*)(Y + ybase + 32 + g * 8 + h * 4) = s3;
  }
}

// ---------- launcher ----------
extern "C" void kernel_launch(void* const* d_in, const int* in_sizes, int n_in,
                              void* d_out, int out_size, void* d_ws, size_t ws_size,
                              hipStream_t stream) {
  (void)in_sizes; (void)n_in; (void)out_size; (void)ws_size;
  const float* x = (const float*)d_in[0];
  const float* w_attn = (const float*)d_in[1];
  const float* w_proj = (const float*)d_in[2];
  float* out = (float*)d_out;

  u16* xb = (u16*)d_ws;                       // [4096][1024] bf16 (reused as Y)
  u16* waT = xb + (u64)M_ * C_;               // [3072][1024]
  u16* wpT = waT + (u64)3 * C_ * C_;          // [1024][1024]
  u16* Qp = wpT + (u64)C_ * C_;               // [32][8][2048][8]
  u16* Kp = Qp + (u64)BH_ * T_ * HD_;
  u16* Vp = Kp + (u64)BH_ * T_ * HD_;         // [32][256][64][8]
  float* ct = (float*)(Vp + (u64)BH_ * T_ * HD_);
  float* st = ct + T_ * 32;
  u16* yb = xb;                               // reuse xb after GEMM1

  rope_table_k<<<256, 256, 0, stream>>>(ct, st);
  cvt_f32_bf16_k<<<(M_ * C_ / 8) / 256, 256, 0, stream>>>(x, xb);
  transpose_w_k<<<dim3(48, 16), 256, 0, stream>>>(w_attn, waT, 3 * C_, C_);
  transpose_w_k<<<dim3(16, 16), 256, 0, stream>>>(w_proj, wpT, C_, C_);

  gemm_bt_k<1><<<dim3(24, 32), 256, 0, stream>>>(xb, waT, nullptr, Qp, Kp, Vp,
                                                 ct, st, M_, 3 * C_, C_);

  attn_fwd_k<<<2048, 64, 0, stream>>>(Qp, Kp, Vp, yb);

  gemm_bt_k<0><<<dim3(8, 32), 256, 0, stream>>>(yb, wpT, out, nullptr, nullptr,
                                                nullptr, nullptr, nullptr,
                                                M_, C_, C_);
}